// Round 6
// baseline (36.991 us; speedup 1.0000x reference)
//
#include <hip/hip_runtime.h>
#include <math.h>

// Problem constants (match reference setup_inputs)
constexpr int B = 32;
constexpr int C = 1024;
constexpr int T = 1024;
constexpr int N = 3;
constexpr int CPB = 16;  // channels per block -> grid = 32*64 = 2048 = 8/CU
constexpr int CPW = 4;   // channels per wave

typedef float f4 __attribute__((ext_vector_type(4)));

__device__ __forceinline__ float wred(float x) {
#pragma unroll
  for (int off = 32; off > 0; off >>= 1) x += __shfl_down(x, off);
  return x;
}

__device__ __forceinline__ float dot4(const f4 a, const f4 b) {
  return a.x * b.x + a.y * b.y + a.z * b.z + a.w * b.w;
}

// ---------------------------------------------------------------------------
// Round 6 = Round 5 with ONE change: plain cached loads instead of
// __builtin_nontemporal_load. Rationale: the video (128 MB) partially lives
// in L2/L3 across graph replays (R4 counters: FETCH 107 MB < 128 MB read);
// nontemporal bypassed that retention and cost ~6 us (R5 regression).
//
// Structure kept from R5:
//   * block = (batch, 16-channel group); 2048 blocks ~ 8/CU co-resident.
//   * prologue: block computes normalized f[b][3][1024] into LDS (12 KB).
//   * main: each wave owns 4 channel rows; ALL 16 float4 loads issued
//     up-front (64 VGPR buffer, max MLP), weights read from LDS once per
//     k-chunk (12 ds_read_b128/wave), FMAs consume both.
//   * single epilogue: 12 independent wave shuffle reductions, lane 0 stores.
// VGPR ~110 < 128 -> no spill (R4 lesson: forcing occupancy caused scratch
// spill = 89 MB HBM writes).
// ---------------------------------------------------------------------------
__global__ __launch_bounds__(256) void tsf_fused(
    const float* __restrict__ v /* [B][C][T] */,
    const int* __restrict__ length,
    const float* __restrict__ center,
    const float* __restrict__ gamma_,
    float* __restrict__ out /* [B][C][N] */) {
  const int groups_per_b = C / CPB;
  const int b = blockIdx.x / groups_per_b;
  const int cg = blockIdx.x % groups_per_b;
  const int lane = threadIdx.x & 63;
  const int wv = threadIdx.x >> 6;

  __shared__ float fs[N][T];    // 12 KB normalized weights
  __shared__ float wsumS[N][4];

  // ---- weight prologue (identical math to round 2) ----
  const float lf = (float)length[b];
  float vals[N][4];
#pragma unroll
  for (int n = 0; n < N; ++n) {
    const float c = tanhf(center[n]);
    const float g = tanhf(gamma_[n]);
    const float ctr = (lf - 1.0f) * (c + 1.0f) * 0.5f;
    const float gam = expf(1.5f - 2.0f * fabsf(g));
    const float inv_gam = 1.0f / gam;
    const float pref = 1.0f / (3.14159265358979f * gam);

    float s = 0.0f;
#pragma unroll
    for (int i = 0; i < 4; ++i) {
      const float t = (float)(threadIdx.x + i * 256);
      const float d = (t - ctr) * inv_gam;
      vals[n][i] = pref / fmaf(d, d, 1.0f);
      s += vals[n][i];
    }
#pragma unroll
    for (int off = 32; off > 0; off >>= 1) s += __shfl_down(s, off);
    if (lane == 0) wsumS[n][wv] = s;
  }
  __syncthreads();
#pragma unroll
  for (int n = 0; n < N; ++n) {
    const float inv =
        1.0f / (wsumS[n][0] + wsumS[n][1] + wsumS[n][2] + wsumS[n][3] + 1e-6f);
#pragma unroll
    for (int i = 0; i < 4; ++i)
      fs[n][threadIdx.x + i * 256] = vals[n][i] * inv;
  }
  __syncthreads();

  // ---- main: issue all 16 cached float4 loads, then consume ----
  const int ch0 = cg * CPB + wv * CPW;
  f4 x[CPW][4];
#pragma unroll
  for (int c = 0; c < CPW; ++c) {
    const f4* row = (const f4*)(v + ((size_t)b * C + ch0 + c) * T);
#pragma unroll
    for (int k = 0; k < 4; ++k) x[c][k] = row[lane + 64 * k];
  }

  const f4* w0 = (const f4*)(&fs[0][0]);
  const f4* w1 = (const f4*)(&fs[1][0]);
  const f4* w2 = (const f4*)(&fs[2][0]);

  float acc[CPW][N];
#pragma unroll
  for (int c = 0; c < CPW; ++c)
#pragma unroll
    for (int n = 0; n < N; ++n) acc[c][n] = 0.0f;

#pragma unroll
  for (int k = 0; k < 4; ++k) {
    const f4 q0 = w0[lane + 64 * k];
    const f4 q1 = w1[lane + 64 * k];
    const f4 q2 = w2[lane + 64 * k];
#pragma unroll
    for (int c = 0; c < CPW; ++c) {
      acc[c][0] += dot4(x[c][k], q0);
      acc[c][1] += dot4(x[c][k], q1);
      acc[c][2] += dot4(x[c][k], q2);
    }
  }

  // ---- epilogue: 12 independent wave reductions, lane 0 stores ----
#pragma unroll
  for (int c = 0; c < CPW; ++c)
#pragma unroll
    for (int n = 0; n < N; ++n) acc[c][n] = wred(acc[c][n]);

  if (lane == 0) {
#pragma unroll
    for (int c = 0; c < CPW; ++c) {
      float* o = out + ((size_t)b * C + ch0 + c) * N;
      o[0] = acc[c][0];
      o[1] = acc[c][1];
      o[2] = acc[c][2];
    }
  }
}

// ---------------------------------------------------------------------------
extern "C" void kernel_launch(void* const* d_in, const int* in_sizes, int n_in,
                              void* d_out, int out_size, void* d_ws,
                              size_t ws_size, hipStream_t stream) {
  const float* video = (const float*)d_in[0];   // (B, C, T, 1, 1) fp32
  const int* length = (const int*)d_in[1];      // (B,) int32
  const float* center = (const float*)d_in[2];  // (N,) fp32
  // d_in[3] = delta (unused by reference)
  const float* gamma_ = (const float*)d_in[4];  // (N,) fp32
  float* out = (float*)d_out;                   // (B, C*N) fp32

  tsf_fused<<<B * (C / CPB), 256, 0, stream>>>(video, length, center, gamma_,
                                               out);
}

// Round 7
// 36.711 us; speedup vs baseline: 1.0076x; 1.0076x over previous
//
#include <hip/hip_runtime.h>
#include <math.h>

// Problem constants (match reference setup_inputs)
constexpr int B = 32;
constexpr int C = 1024;
constexpr int T = 1024;
constexpr int N = 3;
constexpr int CPB = 16;  // channels per block -> grid = 32*64 = 2048 = 8/CU
constexpr int CPW = 4;   // channels per wave

typedef float f4 __attribute__((ext_vector_type(4)));

__device__ __forceinline__ float wred(float x) {
#pragma unroll
  for (int off = 32; off > 0; off >>= 1) x += __shfl_down(x, off);
  return x;
}

__device__ __forceinline__ float dot4(const f4 a, const f4 b) {
  return a.x * b.x + a.y * b.y + a.z * b.z + a.w * b.w;
}

// fast tanh via hardware v_exp_f32: tanh(x) = 1 - 2/(e^{2x}+1)
__device__ __forceinline__ float fast_tanh(float x) {
  const float e = __expf(2.0f * x);
  return 1.0f - 2.0f / (e + 1.0f);
}

// ---------------------------------------------------------------------------
// Round 7 = R2 skeleton (best: 30.0 us) + three targeted edits:
//   1. fast __expf-based tanh/exp in the prologue (R2 used libm tanhf x6 +
//      expf x3 per thread: ~250 redundant VALU instrs; now ~60).
//   2. channel loads 2-deep pipelined (issue ch c+1 before consuming ch c,
//      ping-pong 16-VGPR buffers -> ~8 loads in flight/wave; R3's mistake
//      of 128-VGPR dual full buffers + 48 weight regs is avoided: weights
//      stay in LDS).
//   3. all 12 shuffle reductions deferred to one epilogue (independent
//      chains pipeline on the DS unit; R2 had 18 DEPENDENT bpermutes per
//      channel wedged between load batches).
// VGPR target <= 90 (no spill, 5-6 waves/SIMD). R4 lesson: never force
// occupancy via launch_bounds min-waves.
// ---------------------------------------------------------------------------
__global__ __launch_bounds__(256) void tsf_fused(
    const float* __restrict__ v /* [B][C][T] */,
    const int* __restrict__ length,
    const float* __restrict__ center,
    const float* __restrict__ gamma_,
    float* __restrict__ out /* [B][C][N] */) {
  const int groups_per_b = C / CPB;
  const int b = blockIdx.x / groups_per_b;
  const int cg = blockIdx.x % groups_per_b;
  const int lane = threadIdx.x & 63;
  const int wv = threadIdx.x >> 6;

  __shared__ float fs[N][T];  // 12 KB normalized weights
  __shared__ float wsumS[N][4];

  // ---- weight prologue (fast-math version of R2's) ----
  const float lf = (float)length[b];
  float vals[N][4];
#pragma unroll
  for (int n = 0; n < N; ++n) {
    const float c = fast_tanh(center[n]);
    const float g = fast_tanh(gamma_[n]);
    const float ctr = (lf - 1.0f) * (c + 1.0f) * 0.5f;
    const float gam = __expf(1.5f - 2.0f * fabsf(g));
    const float inv_gam = 1.0f / gam;
    const float pref = 1.0f / (3.14159265358979f * gam);

    float s = 0.0f;
#pragma unroll
    for (int i = 0; i < 4; ++i) {
      const float t = (float)(threadIdx.x + i * 256);
      const float d = (t - ctr) * inv_gam;
      vals[n][i] = pref / fmaf(d, d, 1.0f);
      s += vals[n][i];
    }
#pragma unroll
    for (int off = 32; off > 0; off >>= 1) s += __shfl_down(s, off);
    if (lane == 0) wsumS[n][wv] = s;
  }
  __syncthreads();
#pragma unroll
  for (int n = 0; n < N; ++n) {
    const float inv =
        1.0f / (wsumS[n][0] + wsumS[n][1] + wsumS[n][2] + wsumS[n][3] + 1e-6f);
#pragma unroll
    for (int i = 0; i < 4; ++i)
      fs[n][threadIdx.x + i * 256] = vals[n][i] * inv;
  }
  __syncthreads();

  // ---- main: 4 channels/wave, 2-deep ping-pong load pipeline ----
  const int ch0 = cg * CPB + wv * CPW;
  const f4* r0 = (const f4*)(v + ((size_t)b * C + ch0 + 0) * T);
  const f4* r1 = (const f4*)(v + ((size_t)b * C + ch0 + 1) * T);
  const f4* r2 = (const f4*)(v + ((size_t)b * C + ch0 + 2) * T);
  const f4* r3 = (const f4*)(v + ((size_t)b * C + ch0 + 3) * T);

  const f4* w0 = (const f4*)(&fs[0][0]);
  const f4* w1 = (const f4*)(&fs[1][0]);
  const f4* w2 = (const f4*)(&fs[2][0]);

  float acc[CPW][N];

  f4 xa0 = r0[lane], xa1 = r0[lane + 64], xa2 = r0[lane + 128],
     xa3 = r0[lane + 192];
  f4 xb0 = r1[lane], xb1 = r1[lane + 64], xb2 = r1[lane + 128],
     xb3 = r1[lane + 192];

  // channel 0 (xa), then refill xa <- channel 2
  {
    float a0 = 0.f, a1 = 0.f, a2 = 0.f;
#pragma unroll
    for (int k = 0; k < 4; ++k) {
      const f4 x = (k == 0) ? xa0 : (k == 1) ? xa1 : (k == 2) ? xa2 : xa3;
      a0 += dot4(x, w0[lane + 64 * k]);
      a1 += dot4(x, w1[lane + 64 * k]);
      a2 += dot4(x, w2[lane + 64 * k]);
    }
    acc[0][0] = a0; acc[0][1] = a1; acc[0][2] = a2;
  }
  xa0 = r2[lane]; xa1 = r2[lane + 64]; xa2 = r2[lane + 128];
  xa3 = r2[lane + 192];

  // channel 1 (xb), then refill xb <- channel 3
  {
    float a0 = 0.f, a1 = 0.f, a2 = 0.f;
#pragma unroll
    for (int k = 0; k < 4; ++k) {
      const f4 x = (k == 0) ? xb0 : (k == 1) ? xb1 : (k == 2) ? xb2 : xb3;
      a0 += dot4(x, w0[lane + 64 * k]);
      a1 += dot4(x, w1[lane + 64 * k]);
      a2 += dot4(x, w2[lane + 64 * k]);
    }
    acc[1][0] = a0; acc[1][1] = a1; acc[1][2] = a2;
  }
  xb0 = r3[lane]; xb1 = r3[lane + 64]; xb2 = r3[lane + 128];
  xb3 = r3[lane + 192];

  // channel 2 (xa)
  {
    float a0 = 0.f, a1 = 0.f, a2 = 0.f;
#pragma unroll
    for (int k = 0; k < 4; ++k) {
      const f4 x = (k == 0) ? xa0 : (k == 1) ? xa1 : (k == 2) ? xa2 : xa3;
      a0 += dot4(x, w0[lane + 64 * k]);
      a1 += dot4(x, w1[lane + 64 * k]);
      a2 += dot4(x, w2[lane + 64 * k]);
    }
    acc[2][0] = a0; acc[2][1] = a1; acc[2][2] = a2;
  }
  // channel 3 (xb)
  {
    float a0 = 0.f, a1 = 0.f, a2 = 0.f;
#pragma unroll
    for (int k = 0; k < 4; ++k) {
      const f4 x = (k == 0) ? xb0 : (k == 1) ? xb1 : (k == 2) ? xb2 : xb3;
      a0 += dot4(x, w0[lane + 64 * k]);
      a1 += dot4(x, w1[lane + 64 * k]);
      a2 += dot4(x, w2[lane + 64 * k]);
    }
    acc[3][0] = a0; acc[3][1] = a1; acc[3][2] = a2;
  }

  // ---- epilogue: 12 independent wave reductions, lane 0 stores ----
#pragma unroll
  for (int c = 0; c < CPW; ++c)
#pragma unroll
    for (int n = 0; n < N; ++n) acc[c][n] = wred(acc[c][n]);

  if (lane == 0) {
#pragma unroll
    for (int c = 0; c < CPW; ++c) {
      float* o = out + ((size_t)b * C + ch0 + c) * N;
      o[0] = acc[c][0];
      o[1] = acc[c][1];
      o[2] = acc[c][2];
    }
  }
}

// ---------------------------------------------------------------------------
extern "C" void kernel_launch(void* const* d_in, const int* in_sizes, int n_in,
                              void* d_out, int out_size, void* d_ws,
                              size_t ws_size, hipStream_t stream) {
  const float* video = (const float*)d_in[0];   // (B, C, T, 1, 1) fp32
  const int* length = (const int*)d_in[1];      // (B,) int32
  const float* center = (const float*)d_in[2];  // (N,) fp32
  // d_in[3] = delta (unused by reference)
  const float* gamma_ = (const float*)d_in[4];  // (N,) fp32
  float* out = (float*)d_out;                   // (B, C*N) fp32

  tsf_fused<<<B * (C / CPB), 256, 0, stream>>>(video, length, center, gamma_,
                                               out);
}

// Round 8
// 28.879 us; speedup vs baseline: 1.2809x; 1.2712x over previous
//
#include <hip/hip_runtime.h>
#include <math.h>

// Problem constants (match reference setup_inputs)
constexpr int B = 32;
constexpr int C = 1024;
constexpr int T = 1024;
constexpr int N = 3;
constexpr int CPB = 16;  // channels per block -> grid = 32*64 = 2048 = 8/CU
constexpr int CPW = 4;   // channels per wave

typedef float f4 __attribute__((ext_vector_type(4)));

__device__ __forceinline__ float dot4(const f4 a, const f4 b) {
  return a.x * b.x + a.y * b.y + a.z * b.z + a.w * b.w;
}

// fast tanh via hardware v_exp_f32: tanh(x) = 1 - 2/(e^{2x}+1)
__device__ __forceinline__ float fast_tanh(float x) {
  const float e = __expf(2.0f * x);
  return 1.0f - 2.0f / (e + 1.0f);
}

// ---------------------------------------------------------------------------
// Round 8 = R2 (best, 30.0 us) with strictly VGPR-neutral edits.
// R5-R7 lesson: anything that inflates register live ranges (prefetch
// buffers, deferred reduction state) drops blocks/CU below 8 -> the 2048
// block grid no longer fits in one co-resident generation -> ~6 us slower.
// So: keep R2's per-channel {4 loads -> 48 FMA -> 18-shfl tail -> store}
// loop EXACTLY (small live ranges + natural wave staggering), and only:
//   1. __expf-based tanh/exp prologue (~200 fewer VALU instrs/thread).
//   2. deferred normalization (R3-verified): unnormalized u -> LDS directly;
//      frees vals[3][4] regs, removes one barrier + the normalize pass;
//      scale = pref/(pref*s + 1e-6) folded into the lane-0 stores.
//   3. half-row prefetch (2 float4 = 8 regs, paid by edit 2's -12): HBM
//      stays busy during the all-wave weight prologue; channel 0 peeled.
// ---------------------------------------------------------------------------
__global__ __launch_bounds__(256) void tsf_fused(
    const float* __restrict__ v /* [B][C][T] */,
    const int* __restrict__ length,
    const float* __restrict__ center,
    const float* __restrict__ gamma_,
    float* __restrict__ out /* [B][C][N] */) {
  const int b = blockIdx.x >> 6;  // 64 channel-groups per batch
  const int cg = blockIdx.x & 63;
  const int lane = threadIdx.x & 63;
  const int wv = threadIdx.x >> 6;

  __shared__ float fs[N][T];  // UNNORMALIZED u = 1/(1+d^2), 12 KB
  __shared__ float wsumS[N][4];

  const int ch0 = cg * CPB + wv * CPW;
  const f4* r0 = (const f4*)(v + ((size_t)b * C + ch0) * T);

  // ---- prefetch first half of this wave's first row (kept in 8 regs) ----
  f4 x0 = r0[lane];
  f4 x1 = r0[lane + 64];

  // ---- prologue: unnormalized weights straight to LDS ----
  const float lf = (float)length[b];
  float scale[N];  // pref, later overwritten with final scale
#pragma unroll
  for (int n = 0; n < N; ++n) {
    const float c = fast_tanh(center[n]);
    const float g = fast_tanh(gamma_[n]);
    const float ctr = (lf - 1.0f) * (c + 1.0f) * 0.5f;
    const float gam = __expf(1.5f - 2.0f * fabsf(g));
    const float inv_gam = 1.0f / gam;
    scale[n] = 1.0f / (3.14159265358979f * gam);  // pref

    float s = 0.0f;
#pragma unroll
    for (int i = 0; i < 4; ++i) {
      const float t = (float)(threadIdx.x + i * 256);
      const float d = (t - ctr) * inv_gam;
      const float u = 1.0f / fmaf(d, d, 1.0f);
      fs[n][threadIdx.x + i * 256] = u;
      s += u;
    }
#pragma unroll
    for (int off = 32; off > 0; off >>= 1) s += __shfl_down(s, off);
    if (lane == 0) wsumS[n][wv] = s;
  }
  __syncthreads();

  // scale[n] = pref / (pref * sum_u + 1e-6)
#pragma unroll
  for (int n = 0; n < N; ++n) {
    const float s = wsumS[n][0] + wsumS[n][1] + wsumS[n][2] + wsumS[n][3];
    scale[n] = scale[n] / fmaf(scale[n], s, 1e-6f);
  }

  const f4* w0 = (const f4*)(&fs[0][0]);
  const f4* w1 = (const f4*)(&fs[1][0]);
  const f4* w2 = (const f4*)(&fs[2][0]);

  // ---- peeled channel 0: second half loads now, then consume ----
  {
    const f4 x2 = r0[lane + 128];
    const f4 x3 = r0[lane + 192];

    float a0 = dot4(x0, w0[lane]) + dot4(x1, w0[lane + 64]) +
               dot4(x2, w0[lane + 128]) + dot4(x3, w0[lane + 192]);
    float a1 = dot4(x0, w1[lane]) + dot4(x1, w1[lane + 64]) +
               dot4(x2, w1[lane + 128]) + dot4(x3, w1[lane + 192]);
    float a2 = dot4(x0, w2[lane]) + dot4(x1, w2[lane + 64]) +
               dot4(x2, w2[lane + 128]) + dot4(x3, w2[lane + 192]);

#pragma unroll
    for (int off = 32; off > 0; off >>= 1) {
      a0 += __shfl_down(a0, off);
      a1 += __shfl_down(a1, off);
      a2 += __shfl_down(a2, off);
    }
    if (lane == 0) {
      float* o = out + ((size_t)b * C + ch0) * N;
      o[0] = a0 * scale[0];
      o[1] = a1 * scale[1];
      o[2] = a2 * scale[2];
    }
  }

  // ---- channels 1..3: R2's exact per-channel loop ----
  for (int cc = 1; cc < CPW; ++cc) {
    const int ch = ch0 + cc;
    const f4* row = (const f4*)(v + ((size_t)b * C + ch) * T);

    float a0 = 0.f, a1 = 0.f, a2 = 0.f;
#pragma unroll
    for (int i = lane; i < T / 4; i += 64) {
      const f4 x = row[i];
      a0 += dot4(x, w0[i]);
      a1 += dot4(x, w1[i]);
      a2 += dot4(x, w2[i]);
    }

#pragma unroll
    for (int off = 32; off > 0; off >>= 1) {
      a0 += __shfl_down(a0, off);
      a1 += __shfl_down(a1, off);
      a2 += __shfl_down(a2, off);
    }

    if (lane == 0) {
      float* o = out + ((size_t)b * C + ch) * N;
      o[0] = a0 * scale[0];
      o[1] = a1 * scale[1];
      o[2] = a2 * scale[2];
    }
  }
}

// ---------------------------------------------------------------------------
extern "C" void kernel_launch(void* const* d_in, const int* in_sizes, int n_in,
                              void* d_out, int out_size, void* d_ws,
                              size_t ws_size, hipStream_t stream) {
  const float* video = (const float*)d_in[0];   // (B, C, T, 1, 1) fp32
  const int* length = (const int*)d_in[1];      // (B,) int32
  const float* center = (const float*)d_in[2];  // (N,) fp32
  // d_in[3] = delta (unused by reference)
  const float* gamma_ = (const float*)d_in[4];  // (N,) fp32
  float* out = (float*)d_out;                   // (B, C*N) fp32

  tsf_fused<<<B * (C / CPB), 256, 0, stream>>>(video, length, center, gamma_,
                                               out);
}

// Round 9
// 26.993 us; speedup vs baseline: 1.3704x; 1.0699x over previous
//
#include <hip/hip_runtime.h>
#include <math.h>

// Problem constants (match reference setup_inputs)
constexpr int B = 32;
constexpr int C = 1024;
constexpr int T = 1024;
constexpr int N = 3;
constexpr int BLK = 512;  // 8 waves/block
constexpr int CPB = 32;   // channels per block -> grid = 32*32 = 1024 = 4/CU
constexpr int CPW = 4;    // channels per wave (8 waves x 4 = 32)

typedef float f4 __attribute__((ext_vector_type(4)));

__device__ __forceinline__ float dot4(const f4 a, const f4 b) {
  return a.x * b.x + a.y * b.y + a.z * b.z + a.w * b.w;
}

// fast tanh via hardware v_exp_f32: tanh(x) = 1 - 2/(e^{2x}+1)
__device__ __forceinline__ float fast_tanh(float x) {
  const float e = __expf(2.0f * x);
  return 1.0f - 2.0f / (e + 1.0f);
}

// ---------------------------------------------------------------------------
// Round 9 = R8 (best, 28.9 us) with ONE variable: block 256->512, CPB 16->32.
// Same 32 waves/CU occupancy ceiling (4 blocks x 8 waves), same per-wave
// structure (4 channels, per-channel {burst->FMA->tail->store} -- the
// load-bearing R2 shape), same VGPR. Gains: half the redundant weight
// prologues per CU (4 instead of 8 x ~400 serial cycles), half the launch
// ramp (1024 blocks), half the scalar param loads.
// Kept from R8: fast __expf prologue; deferred normalization (unnormalized
// u -> LDS, scale folded into stores); half-row prefetch of channel 0.
// R5-R7 lesson stands: no big register buffers, no deferred reduce tails.
// ---------------------------------------------------------------------------
__global__ __launch_bounds__(BLK) void tsf_fused(
    const float* __restrict__ v /* [B][C][T] */,
    const int* __restrict__ length,
    const float* __restrict__ center,
    const float* __restrict__ gamma_,
    float* __restrict__ out /* [B][C][N] */) {
  const int groups_per_b = C / CPB;                 // 32
  const int b = blockIdx.x / groups_per_b;
  const int cg = blockIdx.x % groups_per_b;
  const int lane = threadIdx.x & 63;
  const int wv = threadIdx.x >> 6;                  // 0..7

  __shared__ float fs[N][T];   // UNNORMALIZED u = 1/(1+d^2), 12 KB
  __shared__ float wsumS[N][BLK / 64];

  const int ch0 = cg * CPB + wv * CPW;
  const f4* r0 = (const f4*)(v + ((size_t)b * C + ch0) * T);

  // ---- prefetch first half of this wave's first row (8 regs) ----
  f4 x0 = r0[lane];
  f4 x1 = r0[lane + 64];

  // ---- prologue: unnormalized weights straight to LDS ----
  // 512 threads cover T=1024 in 2 strides.
  const float lf = (float)length[b];
  float scale[N];  // pref, later overwritten with final scale
#pragma unroll
  for (int n = 0; n < N; ++n) {
    const float c = fast_tanh(center[n]);
    const float g = fast_tanh(gamma_[n]);
    const float ctr = (lf - 1.0f) * (c + 1.0f) * 0.5f;
    const float gam = __expf(1.5f - 2.0f * fabsf(g));
    const float inv_gam = 1.0f / gam;
    scale[n] = 1.0f / (3.14159265358979f * gam);  // pref

    float s = 0.0f;
#pragma unroll
    for (int i = 0; i < 2; ++i) {
      const float t = (float)(threadIdx.x + i * BLK);
      const float d = (t - ctr) * inv_gam;
      const float u = 1.0f / fmaf(d, d, 1.0f);
      fs[n][threadIdx.x + i * BLK] = u;
      s += u;
    }
#pragma unroll
    for (int off = 32; off > 0; off >>= 1) s += __shfl_down(s, off);
    if (lane == 0) wsumS[n][wv] = s;
  }
  __syncthreads();

  // scale[n] = pref / (pref * sum_u + 1e-6)
#pragma unroll
  for (int n = 0; n < N; ++n) {
    float s = 0.0f;
#pragma unroll
    for (int k = 0; k < BLK / 64; ++k) s += wsumS[n][k];
    scale[n] = scale[n] / fmaf(scale[n], s, 1e-6f);
  }

  const f4* w0 = (const f4*)(&fs[0][0]);
  const f4* w1 = (const f4*)(&fs[1][0]);
  const f4* w2 = (const f4*)(&fs[2][0]);

  // ---- peeled channel 0: second half loads now, then consume ----
  {
    const f4 x2 = r0[lane + 128];
    const f4 x3 = r0[lane + 192];

    float a0 = dot4(x0, w0[lane]) + dot4(x1, w0[lane + 64]) +
               dot4(x2, w0[lane + 128]) + dot4(x3, w0[lane + 192]);
    float a1 = dot4(x0, w1[lane]) + dot4(x1, w1[lane + 64]) +
               dot4(x2, w1[lane + 128]) + dot4(x3, w1[lane + 192]);
    float a2 = dot4(x0, w2[lane]) + dot4(x1, w2[lane + 64]) +
               dot4(x2, w2[lane + 128]) + dot4(x3, w2[lane + 192]);

#pragma unroll
    for (int off = 32; off > 0; off >>= 1) {
      a0 += __shfl_down(a0, off);
      a1 += __shfl_down(a1, off);
      a2 += __shfl_down(a2, off);
    }
    if (lane == 0) {
      float* o = out + ((size_t)b * C + ch0) * N;
      o[0] = a0 * scale[0];
      o[1] = a1 * scale[1];
      o[2] = a2 * scale[2];
    }
  }

  // ---- channels 1..3: the load-bearing R2 per-channel loop ----
  for (int cc = 1; cc < CPW; ++cc) {
    const int ch = ch0 + cc;
    const f4* row = (const f4*)(v + ((size_t)b * C + ch) * T);

    float a0 = 0.f, a1 = 0.f, a2 = 0.f;
#pragma unroll
    for (int i = lane; i < T / 4; i += 64) {
      const f4 x = row[i];
      a0 += dot4(x, w0[i]);
      a1 += dot4(x, w1[i]);
      a2 += dot4(x, w2[i]);
    }

#pragma unroll
    for (int off = 32; off > 0; off >>= 1) {
      a0 += __shfl_down(a0, off);
      a1 += __shfl_down(a1, off);
      a2 += __shfl_down(a2, off);
    }

    if (lane == 0) {
      float* o = out + ((size_t)b * C + ch) * N;
      o[0] = a0 * scale[0];
      o[1] = a1 * scale[1];
      o[2] = a2 * scale[2];
    }
  }
}

// ---------------------------------------------------------------------------
extern "C" void kernel_launch(void* const* d_in, const int* in_sizes, int n_in,
                              void* d_out, int out_size, void* d_ws,
                              size_t ws_size, hipStream_t stream) {
  const float* video = (const float*)d_in[0];   // (B, C, T, 1, 1) fp32
  const int* length = (const int*)d_in[1];      // (B,) int32
  const float* center = (const float*)d_in[2];  // (N,) fp32
  // d_in[3] = delta (unused by reference)
  const float* gamma_ = (const float*)d_in[4];  // (N,) fp32
  float* out = (float*)d_out;                   // (B, C*N) fp32

  tsf_fused<<<B * (C / CPB), BLK, 0, stream>>>(video, length, center, gamma_,
                                               out);
}